// Round 1
// baseline (1400.491 us; speedup 1.0000x reference)
//
#include <hip/hip_runtime.h>
#include <cstddef>

#define H 256
#define NHEADS 8
#define HD 32
#define LMAX 128

// ---------------------------------------------------------------------------
// K1: exclusive prefix sums of src/dst lens (B<=512, single block) + zero stats
// ---------------------------------------------------------------------------
__global__ __launch_bounds__(512) void scan_zero_kernel(
    const int* __restrict__ slen, const int* __restrict__ dlen,
    int* __restrict__ soff, int* __restrict__ doff,
    float* __restrict__ stats, int B)
{
    __shared__ int ss[512], dd[512];
    const int t = threadIdx.x;
    const int sv = (t < B) ? slen[t] : 0;
    const int dv = (t < B) ? dlen[t] : 0;
    ss[t] = sv; dd[t] = dv;
    __syncthreads();
    for (int o = 1; o < 512; o <<= 1) {
        int a = (t >= o) ? ss[t - o] : 0;
        int b = (t >= o) ? dd[t - o] : 0;
        __syncthreads();
        ss[t] += a; dd[t] += b;
        __syncthreads();
    }
    if (t < B) { soff[t] = ss[t] - sv; doff[t] = dd[t] - dv; }
    // zero sum1/sq1/sum2/sq2 (4*256 floats)
    stats[t] = 0.f;
    stats[t + 512] = 0.f;
}

// ---------------------------------------------------------------------------
// K2: attention. One block per (graph, head). 128 threads.
// q = dst (feature d*8+h), k = v = src. softmax over src rows (all valid).
// ---------------------------------------------------------------------------
__global__ __launch_bounds__(128) void attn_kernel(
    const float* __restrict__ src, const float* __restrict__ dst,
    const int* __restrict__ soff, const int* __restrict__ doff,
    const int* __restrict__ slen, const int* __restrict__ dlen,
    float* __restrict__ hmsg)
{
    const int b  = blockIdx.x >> 3;
    const int h  = blockIdx.x & 7;
    const int Ls = slen[b], Ld = dlen[b];
    const int so = soff[b], df = doff[b];
    const int tid = threadIdx.x;

    __shared__ float Ks[LMAX][HD + 1];
    __shared__ float qs[HD];
    __shared__ float sc[LMAX];
    __shared__ float red[LMAX];

    // stage K (=V) slice for this head
    for (int m = tid; m < Ls; m += 128) {
        const float* srow = src + (size_t)(so + m) * H + h;
        #pragma unroll
        for (int d = 0; d < HD; d++) Ks[m][d] = srow[d * NHEADS];
    }
    __syncthreads();

    const float inv_scale = 0.17677669529663687f; // 1/sqrt(32)

    for (int n = 0; n < Ld; n++) {
        if (tid < HD) qs[tid] = dst[(size_t)(df + n) * H + tid * NHEADS + h];
        __syncthreads();

        float s = -INFINITY;
        if (tid < Ls) {
            float acc = 0.f;
            #pragma unroll
            for (int d = 0; d < HD; d++) acc += qs[d] * Ks[tid][d];
            s = acc * inv_scale;
        }
        sc[tid] = s;
        red[tid] = s;
        __syncthreads();
        #pragma unroll
        for (int o = 64; o > 0; o >>= 1) {
            if (tid < o) red[tid] = fmaxf(red[tid], red[tid + o]);
            __syncthreads();
        }
        const float mx = red[0];
        __syncthreads();
        const float e = expf(sc[tid] - mx);   // padded lanes: exp(-inf)=0
        sc[tid] = e;
        red[tid] = e;
        __syncthreads();
        #pragma unroll
        for (int o = 64; o > 0; o >>= 1) {
            if (tid < o) red[tid] += red[tid + o];
            __syncthreads();
        }
        const float rinv = 1.0f / red[0];
        __syncthreads();

        // P·V: thread (d = tid&31, chunk c = tid>>5) partial over m = c, c+4, ...
        const int d = tid & 31, c = tid >> 5;
        float p = 0.f;
        for (int m = c; m < Ls; m += 4) p += sc[m] * Ks[m][d];
        red[tid] = p;
        __syncthreads();
        if (tid < 32) {
            const float o = (red[tid] + red[tid + 32] + red[tid + 64] + red[tid + 96]) * rinv;
            hmsg[(size_t)(df + n) * H + tid * NHEADS + h] = o;
        }
        __syncthreads();
    }
}

// ---------------------------------------------------------------------------
// K3: GEMM1  y1 = [dst_h | hmsg] @ W1^T + b1.  64x64 tile, BK=32, 256 thr, 4x4.
// ---------------------------------------------------------------------------
__global__ __launch_bounds__(256) void gemm1_kernel(
    const float* __restrict__ A0, const float* __restrict__ A1,
    const float* __restrict__ W, const float* __restrict__ bias,
    float* __restrict__ out)
{
    __shared__ float As[32][68];
    __shared__ float Bs[32][68];
    const int tid = threadIdx.x;
    const int rowBase = blockIdx.y * 64;
    const int colBase = blockIdx.x * 64;
    const int tx = tid & 15, ty = tid >> 4;
    float acc[4][4] = {{0.f,0.f,0.f,0.f},{0.f,0.f,0.f,0.f},{0.f,0.f,0.f,0.f},{0.f,0.f,0.f,0.f}};

    for (int phase = 0; phase < 2; phase++) {
        const float* __restrict__ A = phase ? A1 : A0;
        const int wOff = phase * 256;
        for (int kb = 0; kb < 256; kb += 32) {
            #pragma unroll
            for (int half = 0; half < 2; half++) {
                const int l = tid + half * 256;
                const int r = l >> 3, k4 = l & 7;
                const float4 va = *(const float4*)&A[(size_t)(rowBase + r) * 256 + kb + k4 * 4];
                As[k4*4+0][r] = va.x; As[k4*4+1][r] = va.y;
                As[k4*4+2][r] = va.z; As[k4*4+3][r] = va.w;
                const float4 vb = *(const float4*)&W[(size_t)(colBase + r) * 512 + wOff + kb + k4 * 4];
                Bs[k4*4+0][r] = vb.x; Bs[k4*4+1][r] = vb.y;
                Bs[k4*4+2][r] = vb.z; Bs[k4*4+3][r] = vb.w;
            }
            __syncthreads();
            #pragma unroll
            for (int k = 0; k < 32; k++) {
                const float4 a  = *(const float4*)&As[k][ty * 4];
                const float4 bv = *(const float4*)&Bs[k][tx * 4];
                acc[0][0] += a.x*bv.x; acc[0][1] += a.x*bv.y; acc[0][2] += a.x*bv.z; acc[0][3] += a.x*bv.w;
                acc[1][0] += a.y*bv.x; acc[1][1] += a.y*bv.y; acc[1][2] += a.y*bv.z; acc[1][3] += a.y*bv.w;
                acc[2][0] += a.z*bv.x; acc[2][1] += a.z*bv.y; acc[2][2] += a.z*bv.z; acc[2][3] += a.z*bv.w;
                acc[3][0] += a.w*bv.x; acc[3][1] += a.w*bv.y; acc[3][2] += a.w*bv.z; acc[3][3] += a.w*bv.w;
            }
            __syncthreads();
        }
    }
    const float4 bb = *(const float4*)&bias[colBase + tx * 4];
    #pragma unroll
    for (int i = 0; i < 4; i++) {
        float4 o;
        o.x = acc[i][0] + bb.x; o.y = acc[i][1] + bb.y;
        o.z = acc[i][2] + bb.z; o.w = acc[i][3] + bb.w;
        *(float4*)&out[(size_t)(rowBase + ty * 4 + i) * 256 + colBase + tx * 4] = o;
    }
}

// ---------------------------------------------------------------------------
// K5: GEMM2  y2 = relu(y1*scale1+shift1) @ W2^T + b2.  BN1+ReLU folded on load.
// ---------------------------------------------------------------------------
__global__ __launch_bounds__(256) void gemm2_kernel(
    const float* __restrict__ Y1,
    const float* __restrict__ scale1, const float* __restrict__ shift1,
    const float* __restrict__ W, const float* __restrict__ bias,
    float* __restrict__ out)
{
    __shared__ float As[32][68];
    __shared__ float Bs[32][68];
    const int tid = threadIdx.x;
    const int rowBase = blockIdx.y * 64;
    const int colBase = blockIdx.x * 64;
    const int tx = tid & 15, ty = tid >> 4;
    float acc[4][4] = {{0.f,0.f,0.f,0.f},{0.f,0.f,0.f,0.f},{0.f,0.f,0.f,0.f},{0.f,0.f,0.f,0.f}};

    for (int kb = 0; kb < 256; kb += 32) {
        #pragma unroll
        for (int half = 0; half < 2; half++) {
            const int l = tid + half * 256;
            const int r = l >> 3, k4 = l & 7;
            const float4 va = *(const float4*)&Y1[(size_t)(rowBase + r) * 256 + kb + k4 * 4];
            const float4 s4 = *(const float4*)&scale1[kb + k4 * 4];
            const float4 t4 = *(const float4*)&shift1[kb + k4 * 4];
            As[k4*4+0][r] = fmaxf(va.x * s4.x + t4.x, 0.f);
            As[k4*4+1][r] = fmaxf(va.y * s4.y + t4.y, 0.f);
            As[k4*4+2][r] = fmaxf(va.z * s4.z + t4.z, 0.f);
            As[k4*4+3][r] = fmaxf(va.w * s4.w + t4.w, 0.f);
            const float4 vb = *(const float4*)&W[(size_t)(colBase + r) * 256 + kb + k4 * 4];
            Bs[k4*4+0][r] = vb.x; Bs[k4*4+1][r] = vb.y;
            Bs[k4*4+2][r] = vb.z; Bs[k4*4+3][r] = vb.w;
        }
        __syncthreads();
        #pragma unroll
        for (int k = 0; k < 32; k++) {
            const float4 a  = *(const float4*)&As[k][ty * 4];
            const float4 bv = *(const float4*)&Bs[k][tx * 4];
            acc[0][0] += a.x*bv.x; acc[0][1] += a.x*bv.y; acc[0][2] += a.x*bv.z; acc[0][3] += a.x*bv.w;
            acc[1][0] += a.y*bv.x; acc[1][1] += a.y*bv.y; acc[1][2] += a.y*bv.z; acc[1][3] += a.y*bv.w;
            acc[2][0] += a.z*bv.x; acc[2][1] += a.z*bv.y; acc[2][2] += a.z*bv.z; acc[2][3] += a.z*bv.w;
            acc[3][0] += a.w*bv.x; acc[3][1] += a.w*bv.y; acc[3][2] += a.w*bv.z; acc[3][3] += a.w*bv.w;
        }
        __syncthreads();
    }
    const float4 bb = *(const float4*)&bias[colBase + tx * 4];
    #pragma unroll
    for (int i = 0; i < 4; i++) {
        float4 o;
        o.x = acc[i][0] + bb.x; o.y = acc[i][1] + bb.y;
        o.z = acc[i][2] + bb.z; o.w = acc[i][3] + bb.w;
        *(float4*)&out[(size_t)(rowBase + ty * 4 + i) * 256 + colBase + tx * 4] = o;
    }
}

// ---------------------------------------------------------------------------
// K4/K6: per-column sum & sumsq over a 256-row chunk; atomic into stats.
// ---------------------------------------------------------------------------
__global__ __launch_bounds__(256) void colstats_kernel(
    const float* __restrict__ y, float* __restrict__ sum, float* __restrict__ sq,
    int Nrows)
{
    const int c = threadIdx.x;
    const int r0 = blockIdx.x * 256;
    const int r1 = min(r0 + 256, Nrows);
    float s = 0.f, q = 0.f;
    for (int r = r0; r < r1; r++) {
        const float v = y[(size_t)r * 256 + c];
        s += v; q += v * v;
    }
    atomicAdd(&sum[c], s);
    atomicAdd(&sq[c], q);
}

__global__ __launch_bounds__(256) void finalize_kernel(
    const float* __restrict__ sum, const float* __restrict__ sq,
    const float* __restrict__ gamma, const float* __restrict__ beta,
    float* __restrict__ scale, float* __restrict__ shift, int Nrows)
{
    const int c = threadIdx.x;
    const float invN = 1.0f / (float)Nrows;
    const float mean = sum[c] * invN;
    const float var  = sq[c] * invN - mean * mean;
    const float rstd = rsqrtf(var + 1e-5f);
    const float sc   = gamma[c] * rstd;
    scale[c] = sc;
    shift[c] = beta[c] - mean * sc;
}

// ---------------------------------------------------------------------------
// K7: out = dst_h + y2*scale2 + shift2   (vectorized)
// ---------------------------------------------------------------------------
__global__ __launch_bounds__(256) void epilogue_kernel(
    const float* __restrict__ dst, const float* __restrict__ y2,
    const float* __restrict__ scale2, const float* __restrict__ shift2,
    float* __restrict__ out, int total4)
{
    const int i = blockIdx.x * 256 + threadIdx.x;
    if (i >= total4) return;
    const float4 d = ((const float4*)dst)[i];
    const float4 v = ((const float4*)y2)[i];
    const int j0 = (i & 63) * 4;            // feature index of .x
    const float4 s = *(const float4*)&scale2[j0];
    const float4 t = *(const float4*)&shift2[j0];
    float4 o;
    o.x = d.x + v.x * s.x + t.x;
    o.y = d.y + v.y * s.y + t.y;
    o.z = d.z + v.z * s.z + t.z;
    o.w = d.w + v.w * s.w + t.w;
    ((float4*)out)[i] = o;
}

// ---------------------------------------------------------------------------
extern "C" void kernel_launch(void* const* d_in, const int* in_sizes, int n_in,
                              void* d_out, int out_size, void* d_ws, size_t ws_size,
                              hipStream_t stream)
{
    const float* src_h  = (const float*)d_in[0];
    const float* dst_h  = (const float*)d_in[1];
    const int*   slen   = (const int*)d_in[2];
    const int*   dlen   = (const int*)d_in[3];
    const float* W1     = (const float*)d_in[4];
    const float* b1     = (const float*)d_in[5];
    const float* gamma1 = (const float*)d_in[6];
    const float* beta1  = (const float*)d_in[7];
    const float* W2     = (const float*)d_in[8];
    const float* b2     = (const float*)d_in[9];
    const float* gamma2 = (const float*)d_in[10];
    const float* beta2  = (const float*)d_in[11];
    float* out = (float*)d_out;

    const int N = in_sizes[1] / H;     // 40960 rows
    const int B = in_sizes[2];         // 512 graphs

    // workspace layout (floats)
    float* ws    = (float*)d_ws;
    int*   soff  = (int*)d_ws;                 // 512 ints
    int*   doff  = soff + 512;                 // 512 ints
    float* stats = ws + 1024;                  // sum1[256] sq1[256] sum2[256] sq2[256]
    float* scale1 = stats + 1024;
    float* shift1 = scale1 + 256;
    float* scale2 = shift1 + 256;
    float* shift2 = scale2 + 256;
    float* hmsg  = ws + 4096;                  // N*256
    float* y1    = hmsg + (size_t)N * H;       // N*256
    float* y2    = hmsg;                       // reuse hmsg after gemm1

    scan_zero_kernel<<<1, 512, 0, stream>>>(slen, dlen, soff, doff, stats, B);
    attn_kernel<<<B * NHEADS, 128, 0, stream>>>(src_h, dst_h, soff, doff, slen, dlen, hmsg);

    dim3 ggrid(H / 64, N / 64);
    gemm1_kernel<<<ggrid, 256, 0, stream>>>(dst_h, hmsg, W1, b1, y1);
    colstats_kernel<<<(N + 255) / 256, 256, 0, stream>>>(y1, stats + 0, stats + 256, N);
    finalize_kernel<<<1, 256, 0, stream>>>(stats + 0, stats + 256, gamma1, beta1, scale1, shift1, N);

    gemm2_kernel<<<ggrid, 256, 0, stream>>>(y1, scale1, shift1, W2, b2, y2);
    colstats_kernel<<<(N + 255) / 256, 256, 0, stream>>>(y2, stats + 512, stats + 768, N);
    finalize_kernel<<<1, 256, 0, stream>>>(stats + 512, stats + 768, gamma2, beta2, scale2, shift2, N);

    const int total4 = N * H / 4;
    epilogue_kernel<<<(total4 + 255) / 256, 256, 0, stream>>>(dst_h, y2, scale2, shift2, out, total4);
}

// Round 2
// 833.013 us; speedup vs baseline: 1.6812x; 1.6812x over previous
//
#include <hip/hip_runtime.h>
#include <cstddef>

#define H 256
#define NHEADS 8
#define HD 32
#define LMAX 128

// ---------------------------------------------------------------------------
// K1: exclusive prefix sums of src/dst lens (B<=512, single block) + zero stats
// ---------------------------------------------------------------------------
__global__ __launch_bounds__(512) void scan_zero_kernel(
    const int* __restrict__ slen, const int* __restrict__ dlen,
    int* __restrict__ soff, int* __restrict__ doff,
    float* __restrict__ stats, int B)
{
    __shared__ int ss[512], dd[512];
    const int t = threadIdx.x;
    const int sv = (t < B) ? slen[t] : 0;
    const int dv = (t < B) ? dlen[t] : 0;
    ss[t] = sv; dd[t] = dv;
    __syncthreads();
    for (int o = 1; o < 512; o <<= 1) {
        int a = (t >= o) ? ss[t - o] : 0;
        int b = (t >= o) ? dd[t - o] : 0;
        __syncthreads();
        ss[t] += a; dd[t] += b;
        __syncthreads();
    }
    if (t < B) { soff[t] = ss[t] - sv; doff[t] = dd[t] - dv; }
    stats[t] = 0.f;
    stats[t + 512] = 0.f;
}

// ---------------------------------------------------------------------------
// K2: attention, barrier-free after staging. One block per (graph, head),
// 4 waves; wave w owns dst rows n = 2w, 2w+1, then +8. Softmax via
// __shfl_xor (64-lane), PV via per-wave LDS p-scratch (intra-wave DS is
// in-order; asm clobber + wave_barrier pin compiler ordering).
// ---------------------------------------------------------------------------
__global__ __launch_bounds__(256) void attn_kernel(
    const float* __restrict__ src, const float* __restrict__ dst,
    const int* __restrict__ soff, const int* __restrict__ doff,
    const int* __restrict__ slen, const int* __restrict__ dlen,
    float* __restrict__ hmsg)
{
    const int b = blockIdx.x >> 3, h = blockIdx.x & 7;
    const int Ls = slen[b], Ld = dlen[b];
    const int so = soff[b], df = doff[b];
    const int tid = threadIdx.x;
    const int w = tid >> 6, lane = tid & 63;

    __shared__ float Ks[LMAX][HD + 1];   // [m][d], pad -> conflict-free
    __shared__ float2 pp[4][LMAX];       // per-wave (p_n0[m], p_n1[m])

    for (int idx = tid; idx < Ls * HD; idx += 256) {
        const int m = idx >> 5, d = idx & 31;
        Ks[m][d] = src[(size_t)(so + m) * H + d * NHEADS + h];
    }
    __syncthreads();   // the only block barrier

    const float iscale = 0.17677669529663687f; // 1/sqrt(32)
    const int mA = min(lane, Ls - 1);
    const int mB = min(lane + 64, Ls - 1);
    const bool vA = lane < Ls;
    const bool vB = (lane + 64) < Ls;
    const int d = lane & 31, c = lane >> 5;

    for (int n0 = 2 * w; n0 < Ld; n0 += 8) {
        const int n1 = min(n0 + 1, Ld - 1);
        const float* __restrict__ q0p = dst + (size_t)(df + n0) * H + h;
        const float* __restrict__ q1p = dst + (size_t)(df + n1) * H + h;

        // scores for rows mA (and mB if Ls==128), for both queries
        float a0 = 0.f, a1 = 0.f, b0 = 0.f, b1 = 0.f;
        #pragma unroll
        for (int dd = 0; dd < HD; dd++) {
            const float q0 = q0p[dd * NHEADS];
            const float q1 = q1p[dd * NHEADS];
            const float kA = Ks[mA][dd];
            const float kB = Ks[mB][dd];
            a0 += q0 * kA; a1 += q1 * kA;
            b0 += q0 * kB; b1 += q1 * kB;
        }
        float sA0 = vA ? a0 * iscale : -INFINITY;
        float sA1 = vA ? a1 * iscale : -INFINITY;
        float sB0 = vB ? b0 * iscale : -INFINITY;
        float sB1 = vB ? b1 * iscale : -INFINITY;

        float mx0 = fmaxf(sA0, sB0), mx1 = fmaxf(sA1, sB1);
        #pragma unroll
        for (int o = 32; o > 0; o >>= 1) {
            mx0 = fmaxf(mx0, __shfl_xor(mx0, o));
            mx1 = fmaxf(mx1, __shfl_xor(mx1, o));
        }
        const float eA0 = __expf(sA0 - mx0), eA1 = __expf(sA1 - mx1);
        const float eB0 = __expf(sB0 - mx0), eB1 = __expf(sB1 - mx1);
        float sm0 = eA0 + eB0, sm1 = eA1 + eB1;
        #pragma unroll
        for (int o = 32; o > 0; o >>= 1) {
            sm0 += __shfl_xor(sm0, o);
            sm1 += __shfl_xor(sm1, o);
        }
        const float r0 = 1.f / sm0, r1 = 1.f / sm1;

        pp[w][lane]      = make_float2(eA0, eA1);
        pp[w][lane + 64] = make_float2(eB0, eB1);
        __asm__ volatile("" ::: "memory");
        __builtin_amdgcn_wave_barrier();

        // PV: lane (d, c) accumulates m = c, c+2, ... for both queries
        float o0 = 0.f, o1 = 0.f;
        for (int m = c; m < Ls; m += 2) {
            const float kv = Ks[m][d];
            const float2 pv = pp[w][m];
            o0 += pv.x * kv;
            o1 += pv.y * kv;
        }
        __asm__ volatile("" ::: "memory");
        __builtin_amdgcn_wave_barrier();
        o0 += __shfl_xor(o0, 32);
        o1 += __shfl_xor(o1, 32);

        // c==0 lanes store row n0, c==1 lanes store row n1
        const int nst = c ? n1 : n0;
        const float ov = c ? (o1 * r1) : (o0 * r0);
        if (!(c && (n0 + 1 >= Ld)))
            hmsg[(size_t)(df + nst) * H + d * NHEADS + h] = ov;
    }
}

// ---------------------------------------------------------------------------
// K3: GEMM1  y1 = [dst_h | hmsg] @ W1^T + b1.  64x64 tile, BK=32, 256 thr, 4x4.
// ---------------------------------------------------------------------------
__global__ __launch_bounds__(256) void gemm1_kernel(
    const float* __restrict__ A0, const float* __restrict__ A1,
    const float* __restrict__ W, const float* __restrict__ bias,
    float* __restrict__ out)
{
    __shared__ float As[32][68];
    __shared__ float Bs[32][68];
    const int tid = threadIdx.x;
    const int rowBase = blockIdx.y * 64;
    const int colBase = blockIdx.x * 64;
    const int tx = tid & 15, ty = tid >> 4;
    float acc[4][4] = {{0.f,0.f,0.f,0.f},{0.f,0.f,0.f,0.f},{0.f,0.f,0.f,0.f},{0.f,0.f,0.f,0.f}};

    for (int phase = 0; phase < 2; phase++) {
        const float* __restrict__ A = phase ? A1 : A0;
        const int wOff = phase * 256;
        for (int kb = 0; kb < 256; kb += 32) {
            #pragma unroll
            for (int half = 0; half < 2; half++) {
                const int l = tid + half * 256;
                const int r = l >> 3, k4 = l & 7;
                const float4 va = *(const float4*)&A[(size_t)(rowBase + r) * 256 + kb + k4 * 4];
                As[k4*4+0][r] = va.x; As[k4*4+1][r] = va.y;
                As[k4*4+2][r] = va.z; As[k4*4+3][r] = va.w;
                const float4 vb = *(const float4*)&W[(size_t)(colBase + r) * 512 + wOff + kb + k4 * 4];
                Bs[k4*4+0][r] = vb.x; Bs[k4*4+1][r] = vb.y;
                Bs[k4*4+2][r] = vb.z; Bs[k4*4+3][r] = vb.w;
            }
            __syncthreads();
            #pragma unroll
            for (int k = 0; k < 32; k++) {
                const float4 a  = *(const float4*)&As[k][ty * 4];
                const float4 bv = *(const float4*)&Bs[k][tx * 4];
                acc[0][0] += a.x*bv.x; acc[0][1] += a.x*bv.y; acc[0][2] += a.x*bv.z; acc[0][3] += a.x*bv.w;
                acc[1][0] += a.y*bv.x; acc[1][1] += a.y*bv.y; acc[1][2] += a.y*bv.z; acc[1][3] += a.y*bv.w;
                acc[2][0] += a.z*bv.x; acc[2][1] += a.z*bv.y; acc[2][2] += a.z*bv.z; acc[2][3] += a.z*bv.w;
                acc[3][0] += a.w*bv.x; acc[3][1] += a.w*bv.y; acc[3][2] += a.w*bv.z; acc[3][3] += a.w*bv.w;
            }
            __syncthreads();
        }
    }
    const float4 bb = *(const float4*)&bias[colBase + tx * 4];
    #pragma unroll
    for (int i = 0; i < 4; i++) {
        float4 o;
        o.x = acc[i][0] + bb.x; o.y = acc[i][1] + bb.y;
        o.z = acc[i][2] + bb.z; o.w = acc[i][3] + bb.w;
        *(float4*)&out[(size_t)(rowBase + ty * 4 + i) * 256 + colBase + tx * 4] = o;
    }
}

// ---------------------------------------------------------------------------
// K5: GEMM2  y2 = relu(y1*scale1+shift1) @ W2^T + b2.  BN1+ReLU folded on load.
// ---------------------------------------------------------------------------
__global__ __launch_bounds__(256) void gemm2_kernel(
    const float* __restrict__ Y1,
    const float* __restrict__ scale1, const float* __restrict__ shift1,
    const float* __restrict__ W, const float* __restrict__ bias,
    float* __restrict__ out)
{
    __shared__ float As[32][68];
    __shared__ float Bs[32][68];
    const int tid = threadIdx.x;
    const int rowBase = blockIdx.y * 64;
    const int colBase = blockIdx.x * 64;
    const int tx = tid & 15, ty = tid >> 4;
    float acc[4][4] = {{0.f,0.f,0.f,0.f},{0.f,0.f,0.f,0.f},{0.f,0.f,0.f,0.f},{0.f,0.f,0.f,0.f}};

    for (int kb = 0; kb < 256; kb += 32) {
        #pragma unroll
        for (int half = 0; half < 2; half++) {
            const int l = tid + half * 256;
            const int r = l >> 3, k4 = l & 7;
            const float4 va = *(const float4*)&Y1[(size_t)(rowBase + r) * 256 + kb + k4 * 4];
            const float4 s4 = *(const float4*)&scale1[kb + k4 * 4];
            const float4 t4 = *(const float4*)&shift1[kb + k4 * 4];
            As[k4*4+0][r] = fmaxf(va.x * s4.x + t4.x, 0.f);
            As[k4*4+1][r] = fmaxf(va.y * s4.y + t4.y, 0.f);
            As[k4*4+2][r] = fmaxf(va.z * s4.z + t4.z, 0.f);
            As[k4*4+3][r] = fmaxf(va.w * s4.w + t4.w, 0.f);
            const float4 vb = *(const float4*)&W[(size_t)(colBase + r) * 256 + kb + k4 * 4];
            Bs[k4*4+0][r] = vb.x; Bs[k4*4+1][r] = vb.y;
            Bs[k4*4+2][r] = vb.z; Bs[k4*4+3][r] = vb.w;
        }
        __syncthreads();
        #pragma unroll
        for (int k = 0; k < 32; k++) {
            const float4 a  = *(const float4*)&As[k][ty * 4];
            const float4 bv = *(const float4*)&Bs[k][tx * 4];
            acc[0][0] += a.x*bv.x; acc[0][1] += a.x*bv.y; acc[0][2] += a.x*bv.z; acc[0][3] += a.x*bv.w;
            acc[1][0] += a.y*bv.x; acc[1][1] += a.y*bv.y; acc[1][2] += a.y*bv.z; acc[1][3] += a.y*bv.w;
            acc[2][0] += a.z*bv.x; acc[2][1] += a.z*bv.y; acc[2][2] += a.z*bv.z; acc[2][3] += a.z*bv.w;
            acc[3][0] += a.w*bv.x; acc[3][1] += a.w*bv.y; acc[3][2] += a.w*bv.z; acc[3][3] += a.w*bv.w;
        }
        __syncthreads();
    }
    const float4 bb = *(const float4*)&bias[colBase + tx * 4];
    #pragma unroll
    for (int i = 0; i < 4; i++) {
        float4 o;
        o.x = acc[i][0] + bb.x; o.y = acc[i][1] + bb.y;
        o.z = acc[i][2] + bb.z; o.w = acc[i][3] + bb.w;
        *(float4*)&out[(size_t)(rowBase + ty * 4 + i) * 256 + colBase + tx * 4] = o;
    }
}

// ---------------------------------------------------------------------------
// K4/K6: per-column sum & sumsq over a 256-row chunk; atomic into stats.
// ---------------------------------------------------------------------------
__global__ __launch_bounds__(256) void colstats_kernel(
    const float* __restrict__ y, float* __restrict__ sum, float* __restrict__ sq,
    int Nrows)
{
    const int c = threadIdx.x;
    const int r0 = blockIdx.x * 256;
    const int r1 = min(r0 + 256, Nrows);
    float s = 0.f, q = 0.f;
    for (int r = r0; r < r1; r++) {
        const float v = y[(size_t)r * 256 + c];
        s += v; q += v * v;
    }
    atomicAdd(&sum[c], s);
    atomicAdd(&sq[c], q);
}

__global__ __launch_bounds__(256) void finalize_kernel(
    const float* __restrict__ sum, const float* __restrict__ sq,
    const float* __restrict__ gamma, const float* __restrict__ beta,
    float* __restrict__ scale, float* __restrict__ shift, int Nrows)
{
    const int c = threadIdx.x;
    const float invN = 1.0f / (float)Nrows;
    const float mean = sum[c] * invN;
    const float var  = sq[c] * invN - mean * mean;
    const float rstd = rsqrtf(var + 1e-5f);
    const float sc   = gamma[c] * rstd;
    scale[c] = sc;
    shift[c] = beta[c] - mean * sc;
}

// ---------------------------------------------------------------------------
// K7: out = dst_h + y2*scale2 + shift2   (vectorized)
// ---------------------------------------------------------------------------
__global__ __launch_bounds__(256) void epilogue_kernel(
    const float* __restrict__ dst, const float* __restrict__ y2,
    const float* __restrict__ scale2, const float* __restrict__ shift2,
    float* __restrict__ out, int total4)
{
    const int i = blockIdx.x * 256 + threadIdx.x;
    if (i >= total4) return;
    const float4 d = ((const float4*)dst)[i];
    const float4 v = ((const float4*)y2)[i];
    const int j0 = (i & 63) * 4;
    const float4 s = *(const float4*)&scale2[j0];
    const float4 t = *(const float4*)&shift2[j0];
    float4 o;
    o.x = d.x + v.x * s.x + t.x;
    o.y = d.y + v.y * s.y + t.y;
    o.z = d.z + v.z * s.z + t.z;
    o.w = d.w + v.w * s.w + t.w;
    ((float4*)out)[i] = o;
}

// ---------------------------------------------------------------------------
extern "C" void kernel_launch(void* const* d_in, const int* in_sizes, int n_in,
                              void* d_out, int out_size, void* d_ws, size_t ws_size,
                              hipStream_t stream)
{
    const float* src_h  = (const float*)d_in[0];
    const float* dst_h  = (const float*)d_in[1];
    const int*   slen   = (const int*)d_in[2];
    const int*   dlen   = (const int*)d_in[3];
    const float* W1     = (const float*)d_in[4];
    const float* b1     = (const float*)d_in[5];
    const float* gamma1 = (const float*)d_in[6];
    const float* beta1  = (const float*)d_in[7];
    const float* W2     = (const float*)d_in[8];
    const float* b2     = (const float*)d_in[9];
    const float* gamma2 = (const float*)d_in[10];
    const float* beta2  = (const float*)d_in[11];
    float* out = (float*)d_out;

    const int N = in_sizes[1] / H;     // 40960 rows
    const int B = in_sizes[2];         // 512 graphs

    float* ws    = (float*)d_ws;
    int*   soff  = (int*)d_ws;                 // 512 ints
    int*   doff  = soff + 512;                 // 512 ints
    float* stats = ws + 1024;                  // sum1[256] sq1[256] sum2[256] sq2[256]
    float* scale1 = stats + 1024;
    float* shift1 = scale1 + 256;
    float* scale2 = shift1 + 256;
    float* shift2 = scale2 + 256;
    float* hmsg  = ws + 4096;                  // N*256
    float* y1    = hmsg + (size_t)N * H;       // N*256
    float* y2    = hmsg;                       // reuse hmsg after gemm1

    scan_zero_kernel<<<1, 512, 0, stream>>>(slen, dlen, soff, doff, stats, B);
    attn_kernel<<<B * NHEADS, 256, 0, stream>>>(src_h, dst_h, soff, doff, slen, dlen, hmsg);

    dim3 ggrid(H / 64, N / 64);
    gemm1_kernel<<<ggrid, 256, 0, stream>>>(dst_h, hmsg, W1, b1, y1);
    colstats_kernel<<<(N + 255) / 256, 256, 0, stream>>>(y1, stats + 0, stats + 256, N);
    finalize_kernel<<<1, 256, 0, stream>>>(stats + 0, stats + 256, gamma1, beta1, scale1, shift1, N);

    gemm2_kernel<<<ggrid, 256, 0, stream>>>(y1, scale1, shift1, W2, b2, y2);
    colstats_kernel<<<(N + 255) / 256, 256, 0, stream>>>(y2, stats + 512, stats + 768, N);
    finalize_kernel<<<1, 256, 0, stream>>>(stats + 512, stats + 768, gamma2, beta2, scale2, shift2, N);

    const int total4 = N * H / 4;
    epilogue_kernel<<<(total4 + 255) / 256, 256, 0, stream>>>(dst_h, y2, scale2, shift2, out, total4);
}